// Round 9
// baseline (267.007 us; speedup 1.0000x reference)
//
#include <hip/hip_runtime.h>
#include <hip/hip_bf16.h>

#define NN 50000
#define NE 800000
#define HF 128

// workspace byte offsets (256-aligned), total 43,868,672 B (~41.8 MB, proven in R2)
#define OFF_FLAG   0u
#define OFF_ROWPTR 256u         // 50001 * 4 = 200004 used; region ends 200704
#define OFF_BSUM   200272u      // 49*4 bsum + pad -> fits in rowptr region slack
#define OFF_BOFF   200480u      // 49*4 boff; 200480+196=200676 <= 200704 OK
#define OFF_DEG    200704u      // 50000 * 4 (unused; kept for layout stability)
#define OFF_FILL   400896u      // 50000 * 4
#define OFF_ADJ    601088u      // 800000 * 4
#define OFF_FX     3801088u     // 6,400,000 bf16 (canonical feats)
#define OFF_WC1    16601088u    // 16384 bf16
#define OFF_WC2    16633856u    // 16384 bf16
#define OFF_PAR    16666624u    // 8 slots * 256 B: al1,ar1,b1,al2,ar2,b2,Wp,bp
#define OFF_Z      16668672u    // 6,400,000 bf16; ALSO reused as rank[NE] scratch pre-GEMM
#define OFF_H1     29468672u    // 6,400,000 bf16
#define OFF_EL     42268672u    // 200000 f32
#define OFF_ER     43068672u    // 200000 f32

typedef __hip_bfloat16 bf16;
typedef unsigned short us16;

#define N_SMALL 33569  // 16384+16384+6*128+32+1 elements in k_canon_small

typedef __attribute__((ext_vector_type(8))) short bf16x8;   // MFMA A/B frag (4 VGPRs)
typedef __attribute__((ext_vector_type(4))) float f32x4;    // MFMA C/D frag

__device__ __forceinline__ float us2f(us16 u) {
  union { unsigned int i; float f; } c; c.i = ((unsigned int)u) << 16; return c.f;
}
__device__ __forceinline__ us16 f2us(float f) {
  bf16 h = __float2bfloat16(f);
  union { bf16 h; us16 u; } c; c.h = h; return c.u;
}
__device__ __forceinline__ float blo(unsigned v) {  // low bf16 of a dword
  union { unsigned i; float f; } c; c.i = v << 16; return c.f;
}
__device__ __forceinline__ float bhi(unsigned v) {  // high bf16 of a dword
  union { unsigned i; float f; } c; c.i = v & 0xffff0000u; return c.f;
}
__device__ __forceinline__ unsigned pk2(float a, float b) {
  return (unsigned)f2us(a) | ((unsigned)f2us(b) << 16);
}

// ---- dtype detection: bf16 inputs have exponent field <= ~126 (|w|<1);
// f32 inputs read as ushort have uniform low-halves -> exp >= 135 certain.
__global__ __launch_bounds__(64) void k_detect(const void* __restrict__ w1raw,
                                               int* __restrict__ flag) {
  const us16* u = (const us16*)w1raw;
  int lane = threadIdx.x;
  int mx = 0;
  for (int i = lane; i < 2048; i += 64) {
    int e = (u[i] >> 7) & 0xFF;
    mx = mx > e ? mx : e;
  }
#pragma unroll
  for (int m = 32; m >= 1; m >>= 1) {
    int o = __shfl_xor(mx, m);
    mx = mx > o ? mx : o;
  }
  if (lane == 0) *flag = (mx >= 135) ? 1 : 0;  // 1 = inputs are f32
}

__global__ __launch_bounds__(256) void k_canon_feats(const void* __restrict__ src,
                                                     us16* __restrict__ dst,
                                                     const int* __restrict__ flag) {
  int i = (blockIdx.x * 256 + threadIdx.x) * 4;
  if (i >= NN * HF) return;
  if (*flag) {
    float4 v = *(const float4*)((const float*)src + i);
    ushort4 o;
    o.x = f2us(v.x); o.y = f2us(v.y); o.z = f2us(v.z); o.w = f2us(v.w);
    *(ushort4*)(dst + i) = o;
  } else {
    *(ushort4*)(dst + i) = *(const ushort4*)((const us16*)src + i);
  }
}

// parallel small-param canonicalization: grid covers all N_SMALL elems
__global__ __launch_bounds__(256) void k_canon_small(
    const void* s0, const void* s1, const void* s2, const void* s3, const void* s4,
    const void* s5, const void* s6, const void* s7, const void* s8, const void* s9,
    us16* d0, us16* d1, us16* d2, us16* d3, us16* d4,
    us16* d5, us16* d6, us16* d7, us16* d8, us16* d9,
    const int* __restrict__ flag) {
  const void* sp[10] = {s0, s1, s2, s3, s4, s5, s6, s7, s8, s9};
  us16* dp[10] = {d0, d1, d2, d3, d4, d5, d6, d7, d8, d9};
  const int cnt[10] = {16384, 16384, 128, 128, 128, 128, 128, 128, 32, 1};
  int f = *flag;
  int gid = blockIdx.x * 256 + threadIdx.x;
  int base = 0;
#pragma unroll
  for (int p = 0; p < 10; ++p) {
    int loc = gid - base;
    if (loc >= 0 && loc < cnt[p])
      dp[p][loc] = f ? f2us(((const float*)sp[p])[loc]) : ((const us16*)sp[p])[loc];
    base += cnt[p];
  }
}

// ---- CSR build (rank/place: one atomic pass, atomic-free placement)
__global__ void k_rank(const int* __restrict__ dst, int* __restrict__ fill,
                       int* __restrict__ rank) {
  int e = blockIdx.x * 256 + threadIdx.x;
  if (e < NE) rank[e] = atomicAdd(&fill[dst[e]], 1);
}

// hierarchical scan phase 1: per-block (1024 nodes) degree sums
__global__ __launch_bounds__(1024) void k_s1(const int* __restrict__ deg,
                                             int* __restrict__ bsum) {
  __shared__ int red[1024];
  int t = threadIdx.x;
  int i = blockIdx.x * 1024 + t;
  red[t] = (i < NN) ? deg[i] : 0;
  __syncthreads();
  for (int s = 512; s > 0; s >>= 1) {
    if (t < s) red[t] += red[t + s];
    __syncthreads();
  }
  if (t == 0) bsum[blockIdx.x] = red[0];
}

// phase 2: one wave scans the 49 block sums -> exclusive block offsets
__global__ __launch_bounds__(64) void k_s2(const int* __restrict__ bsum,
                                           int* __restrict__ boff,
                                           int* __restrict__ rowptr) {
  int lane = threadIdx.x;
  const int NB = (NN + 1023) / 1024;  // 49
  int v = (lane < NB) ? bsum[lane] : 0;
  int orig = v;
#pragma unroll
  for (int off = 1; off < 64; off <<= 1) {
    int u = __shfl_up(v, off);
    if (lane >= off) v += u;
  }
  if (lane < NB) boff[lane] = v - orig;  // exclusive
  if (lane == 0) rowptr[NN] = NE;
}

// phase 3: per-block Hillis-Steele exclusive scan + block offset -> rowptr
__global__ __launch_bounds__(1024) void k_s3(const int* __restrict__ deg,
                                             const int* __restrict__ boff,
                                             int* __restrict__ rowptr) {
  __shared__ int part[1024];
  int t = threadIdx.x;
  int i = blockIdx.x * 1024 + t;
  int d = (i < NN) ? deg[i] : 0;
  part[t] = d;
  __syncthreads();
  for (int off = 1; off < 1024; off <<= 1) {
    int v = (t >= off) ? part[t - off] : 0;
    __syncthreads();
    part[t] += v;
    __syncthreads();
  }
  if (i < NN) rowptr[i] = boff[blockIdx.x] + part[t] - d;
}

// atomic-free placement: adj[rowptr[d] + rank[e]] = src[e]
__global__ void k_place(const int* __restrict__ src, const int* __restrict__ dst,
                        const int* __restrict__ rowptr, const int* __restrict__ rank,
                        int* __restrict__ adj) {
  int e = blockIdx.x * 256 + threadIdx.x;
  if (e < NE) adj[rowptr[dst[e]] + rank[e]] = src[e];
}

// ---- MFMA GEMM + fused attention-coefficient epilogue.
// Z[N,128](bf16) = X[N,128](bf16) @ W[128,128](bf16); el/er[N,4](f32) from the
// f32 accumulators (closer to the f32 reference than re-reading bf16 Z).
// 16x16x32 bf16 MFMA. Block = 256 thr = 4 waves; each wave does 16 rows x 128 cols.
// W repacked into LDS in B-fragment order (one ds_read_b128 per (ntile,kstep)).
// Fragment maps (m89/m120-verified): A[m=lane&15][k=q*8+j], B[k=q*8+j][n=lane&15],
// D row=q*4+reg, col=t*16+c.
__global__ __launch_bounds__(256) void k_gemm(const us16* __restrict__ X,
                                              const us16* __restrict__ W,
                                              us16* __restrict__ Z,
                                              const us16* __restrict__ al,
                                              const us16* __restrict__ ar,
                                              float* __restrict__ el,
                                              float* __restrict__ er) {
  __shared__ us16 Wl[HF * HF];
  int tid = threadIdx.x;
  // repack W (16384 elems, 64 per thread; coalesced 2B global reads)
  for (int e = tid; e < HF * HF; e += 256) {
    int k = e >> 7, n = e & 127;
    int d = ((((k >> 5) * 8 + (n >> 4)) * 4 + ((k >> 3) & 3)) * 16 + (n & 15)) * 8 + (k & 7);
    Wl[d] = W[e];
  }
  __syncthreads();

  int w = tid >> 6;        // wave 0..3
  int lane = tid & 63;
  int q = lane >> 4;       // quad 0..3
  int c = lane & 15;       // col-in-tile / row-in-tile
  int m0 = blockIdx.x * 64 + w * 16;

  int rA = m0 + c;                       // A-frag row for this lane
  if (rA >= NN) rA = NN - 1;             // clamp (stores are guarded)
  const us16* xrow = X + (size_t)rA * HF;

  f32x4 acc[8] = {};
#pragma unroll
  for (int s = 0; s < 4; ++s) {
    bf16x8 a = *(const bf16x8*)&xrow[s * 32 + q * 8];
#pragma unroll
    for (int t = 0; t < 8; ++t) {
      bf16x8 b = *(const bf16x8*)&Wl[((((s * 8) + t) * 4 + q) * 16 + c) * 8];
      acc[t] = __builtin_amdgcn_mfma_f32_16x16x32_bf16(a, b, acc[t], 0, 0, 0);
    }
  }

  // Z store
#pragma unroll
  for (int reg = 0; reg < 4; ++reg) {
    int row = m0 + q * 4 + reg;
    if (row < NN) {
      us16* zrow = Z + (size_t)row * HF;
#pragma unroll
      for (int t = 0; t < 8; ++t) zrow[t * 16 + c] = f2us(acc[t][reg]);
    }
  }

  // fused coef epilogue: col = t*16+c belongs to head t>>1; al/ar indexed by col.
  float alv[8], arv[8];
#pragma unroll
  for (int t = 0; t < 8; ++t) {
    alv[t] = us2f(al[t * 16 + c]);
    arv[t] = us2f(ar[t * 16 + c]);
  }
#pragma unroll
  for (int reg = 0; reg < 4; ++reg) {
    int row = m0 + q * 4 + reg;
    float pl[4], pr[4];
#pragma unroll
    for (int h = 0; h < 4; ++h) {
      pl[h] = acc[2 * h][reg] * alv[2 * h] + acc[2 * h + 1][reg] * alv[2 * h + 1];
      pr[h] = acc[2 * h][reg] * arv[2 * h] + acc[2 * h + 1][reg] * arv[2 * h + 1];
    }
#pragma unroll
    for (int m = 1; m < 16; m <<= 1) {
#pragma unroll
      for (int h = 0; h < 4; ++h) {
        pl[h] += __shfl_xor(pl[h], m);
        pr[h] += __shfl_xor(pr[h], m);
      }
    }
    if (row < NN) {
      int cc = c & 3;
      float vl = cc == 0 ? pl[0] : cc == 1 ? pl[1] : cc == 2 ? pl[2] : pl[3];
      float vr = cc == 0 ? pr[0] : cc == 1 ? pr[1] : cc == 2 ? pr[2] : pr[3];
      if (c < 4) el[row * 4 + cc] = vl;
      else if (c < 8) er[row * 4 + cc] = vr;
    }
  }
}

// One wave per destination node; 4 nodes per 256-thread block (no barriers).
// Wave layout: 4 edge-groups (g=lane>>4) x 16 feature-lanes (p=lane&15).
// Each lane owns 8 features f0=p*8 (one uint4 = 16B load), head hl=p>>2.
// No max pass (scores O(+-10), exp can't overflow f32; softmax shift-invariant).
// R9: 4-wide unroll -> 4 outstanding adj/el/Z gather chains per group (avg
// deg=16 means one 4-wide iteration covers the typical row per group).
template <int LAYER>
__global__ __launch_bounds__(256) void k_agg(
    const us16* __restrict__ Z, const float* __restrict__ el,
    const float* __restrict__ er, const int* __restrict__ rowptr,
    const int* __restrict__ adj, const us16* __restrict__ resid,
    const us16* __restrict__ bias, us16* __restrict__ Hout,
    const us16* __restrict__ Wp, const us16* __restrict__ bp,
    void* __restrict__ out, const int* __restrict__ flag) {
  int n = blockIdx.x * 4 + (threadIdx.x >> 6);  // NN = 50000 = 12500*4 exact
  int lane = threadIdx.x & 63;
  int g = lane >> 4;   // edge group 0..3
  int p = lane & 15;   // feature position 0..15
  int hl = p >> 2;     // head owning this lane's features
  int f0 = p * 8;      // first of 8 features
  int begin = rowptr[n];
  int deg = rowptr[n + 1] - begin;
  float erh = er[n * 4 + hl];

  float acc[8] = {};
  float ssum = 0.f;
  int i = g;
  for (; i + 12 < deg; i += 16) {  // 4 edges per group-iteration, loads paired
    int s0 = adj[begin + i];
    int s1 = adj[begin + i + 4];
    int s2 = adj[begin + i + 8];
    int s3 = adj[begin + i + 12];
    float l0 = el[s0 * 4 + hl];
    float l1 = el[s1 * 4 + hl];
    float l2 = el[s2 * 4 + hl];
    float l3 = el[s3 * 4 + hl];
    uint4 za = *(const uint4*)&Z[(size_t)s0 * HF + f0];
    uint4 zb = *(const uint4*)&Z[(size_t)s1 * HF + f0];
    uint4 zc = *(const uint4*)&Z[(size_t)s2 * HF + f0];
    uint4 zd = *(const uint4*)&Z[(size_t)s3 * HF + f0];
    float sc0 = l0 + erh; sc0 = sc0 > 0.f ? sc0 : 0.2f * sc0;
    float sc1 = l1 + erh; sc1 = sc1 > 0.f ? sc1 : 0.2f * sc1;
    float sc2 = l2 + erh; sc2 = sc2 > 0.f ? sc2 : 0.2f * sc2;
    float sc3 = l3 + erh; sc3 = sc3 > 0.f ? sc3 : 0.2f * sc3;
    float ex0 = __expf(sc0);
    float ex1 = __expf(sc1);
    float ex2 = __expf(sc2);
    float ex3 = __expf(sc3);
    ssum += (ex0 + ex1) + (ex2 + ex3);
    acc[0] = fmaf(ex0, blo(za.x), acc[0]); acc[1] = fmaf(ex0, bhi(za.x), acc[1]);
    acc[2] = fmaf(ex0, blo(za.y), acc[2]); acc[3] = fmaf(ex0, bhi(za.y), acc[3]);
    acc[4] = fmaf(ex0, blo(za.z), acc[4]); acc[5] = fmaf(ex0, bhi(za.z), acc[5]);
    acc[6] = fmaf(ex0, blo(za.w), acc[6]); acc[7] = fmaf(ex0, bhi(za.w), acc[7]);
    acc[0] = fmaf(ex1, blo(zb.x), acc[0]); acc[1] = fmaf(ex1, bhi(zb.x), acc[1]);
    acc[2] = fmaf(ex1, blo(zb.y), acc[2]); acc[3] = fmaf(ex1, bhi(zb.y), acc[3]);
    acc[4] = fmaf(ex1, blo(zb.z), acc[4]); acc[5] = fmaf(ex1, bhi(zb.z), acc[5]);
    acc[6] = fmaf(ex1, blo(zb.w), acc[6]); acc[7] = fmaf(ex1, bhi(zb.w), acc[7]);
    acc[0] = fmaf(ex2, blo(zc.x), acc[0]); acc[1] = fmaf(ex2, bhi(zc.x), acc[1]);
    acc[2] = fmaf(ex2, blo(zc.y), acc[2]); acc[3] = fmaf(ex2, bhi(zc.y), acc[3]);
    acc[4] = fmaf(ex2, blo(zc.z), acc[4]); acc[5] = fmaf(ex2, bhi(zc.z), acc[5]);
    acc[6] = fmaf(ex2, blo(zc.w), acc[6]); acc[7] = fmaf(ex2, bhi(zc.w), acc[7]);
    acc[0] = fmaf(ex3, blo(zd.x), acc[0]); acc[1] = fmaf(ex3, bhi(zd.x), acc[1]);
    acc[2] = fmaf(ex3, blo(zd.y), acc[2]); acc[3] = fmaf(ex3, bhi(zd.y), acc[3]);
    acc[4] = fmaf(ex3, blo(zd.z), acc[4]); acc[5] = fmaf(ex3, bhi(zd.z), acc[5]);
    acc[6] = fmaf(ex3, blo(zd.w), acc[6]); acc[7] = fmaf(ex3, bhi(zd.w), acc[7]);
  }
  for (; i + 4 < deg; i += 8) {  // 2-wide tail
    int s0 = adj[begin + i];
    int s1 = adj[begin + i + 4];
    float l0 = el[s0 * 4 + hl];
    float l1 = el[s1 * 4 + hl];
    uint4 za = *(const uint4*)&Z[(size_t)s0 * HF + f0];
    uint4 zb = *(const uint4*)&Z[(size_t)s1 * HF + f0];
    float sc0 = l0 + erh; sc0 = sc0 > 0.f ? sc0 : 0.2f * sc0;
    float sc1 = l1 + erh; sc1 = sc1 > 0.f ? sc1 : 0.2f * sc1;
    float ex0 = __expf(sc0);
    float ex1 = __expf(sc1);
    ssum += ex0 + ex1;
    acc[0] = fmaf(ex0, blo(za.x), acc[0]); acc[1] = fmaf(ex0, bhi(za.x), acc[1]);
    acc[2] = fmaf(ex0, blo(za.y), acc[2]); acc[3] = fmaf(ex0, bhi(za.y), acc[3]);
    acc[4] = fmaf(ex0, blo(za.z), acc[4]); acc[5] = fmaf(ex0, bhi(za.z), acc[5]);
    acc[6] = fmaf(ex0, blo(za.w), acc[6]); acc[7] = fmaf(ex0, bhi(za.w), acc[7]);
    acc[0] = fmaf(ex1, blo(zb.x), acc[0]); acc[1] = fmaf(ex1, bhi(zb.x), acc[1]);
    acc[2] = fmaf(ex1, blo(zb.y), acc[2]); acc[3] = fmaf(ex1, bhi(zb.y), acc[3]);
    acc[4] = fmaf(ex1, blo(zb.z), acc[4]); acc[5] = fmaf(ex1, bhi(zb.z), acc[5]);
    acc[6] = fmaf(ex1, blo(zb.w), acc[6]); acc[7] = fmaf(ex1, bhi(zb.w), acc[7]);
  }
  if (i < deg) {  // final edge for this group
    int s = adj[begin + i];
    float sc = el[s * 4 + hl] + erh;
    sc = sc > 0.f ? sc : 0.2f * sc;
    float ex = __expf(sc);
    ssum += ex;
    uint4 zq = *(const uint4*)&Z[(size_t)s * HF + f0];
    acc[0] = fmaf(ex, blo(zq.x), acc[0]); acc[1] = fmaf(ex, bhi(zq.x), acc[1]);
    acc[2] = fmaf(ex, blo(zq.y), acc[2]); acc[3] = fmaf(ex, bhi(zq.y), acc[3]);
    acc[4] = fmaf(ex, blo(zq.z), acc[4]); acc[5] = fmaf(ex, bhi(zq.z), acc[5]);
    acc[6] = fmaf(ex, blo(zq.w), acc[6]); acc[7] = fmaf(ex, bhi(zq.w), acc[7]);
  }
  // combine the 4 edge-groups (lanes l, l^16, l^32, l^48 share p -> same feats/head)
  ssum += __shfl_xor(ssum, 16); ssum += __shfl_xor(ssum, 32);
#pragma unroll
  for (int j = 0; j < 8; ++j) {
    acc[j] += __shfl_xor(acc[j], 16);
    acc[j] += __shfl_xor(acc[j], 32);
  }
  float inv = 1.f / fmaxf(ssum, 1e-9f);  // deg==0 -> acc==0 -> r==0 (matches ref)

  uint4 xq = *(const uint4*)&resid[(size_t)n * HF + f0];
  uint4 bq = *(const uint4*)&bias[f0];
  float t0 = fmaf(acc[0], inv, blo(xq.x) + blo(bq.x));
  float t1 = fmaf(acc[1], inv, bhi(xq.x) + bhi(bq.x));
  float t2 = fmaf(acc[2], inv, blo(xq.y) + blo(bq.y));
  float t3 = fmaf(acc[3], inv, bhi(xq.y) + bhi(bq.y));
  float t4 = fmaf(acc[4], inv, blo(xq.z) + blo(bq.z));
  float t5 = fmaf(acc[5], inv, bhi(xq.z) + bhi(bq.z));
  float t6 = fmaf(acc[6], inv, blo(xq.w) + blo(bq.w));
  float t7 = fmaf(acc[7], inv, bhi(xq.w) + bhi(bq.w));

  if (LAYER == 1) {
    t0 = t0 > 0.f ? t0 : __expf(t0) - 1.f;  // ELU
    t1 = t1 > 0.f ? t1 : __expf(t1) - 1.f;
    t2 = t2 > 0.f ? t2 : __expf(t2) - 1.f;
    t3 = t3 > 0.f ? t3 : __expf(t3) - 1.f;
    t4 = t4 > 0.f ? t4 : __expf(t4) - 1.f;
    t5 = t5 > 0.f ? t5 : __expf(t5) - 1.f;
    t6 = t6 > 0.f ? t6 : __expf(t6) - 1.f;
    t7 = t7 > 0.f ? t7 : __expf(t7) - 1.f;
    if (g == 0) {
      uint4 o;
      o.x = pk2(t0, t1); o.y = pk2(t2, t3); o.z = pk2(t4, t5); o.w = pk2(t6, t7);
      *(uint4*)&Hout[(size_t)n * HF + f0] = o;
    }
  } else {
    // mean over heads: lanes {p, p^4, p^8, p^12} hold same within-head feats
    t0 += __shfl_xor(t0, 4); t0 += __shfl_xor(t0, 8);
    t1 += __shfl_xor(t1, 4); t1 += __shfl_xor(t1, 8);
    t2 += __shfl_xor(t2, 4); t2 += __shfl_xor(t2, 8);
    t3 += __shfl_xor(t3, 4); t3 += __shfl_xor(t3, 8);
    t4 += __shfl_xor(t4, 4); t4 += __shfl_xor(t4, 8);
    t5 += __shfl_xor(t5, 4); t5 += __shfl_xor(t5, 8);
    t6 += __shfl_xor(t6, 4); t6 += __shfl_xor(t6, 8);
    t7 += __shfl_xor(t7, 4); t7 += __shfl_xor(t7, 8);
    // projection over the 32 mean features: lane p&3 holds feats (p&3)*8..+7
    int fw = (p & 3) * 8;
    float pr = 0.25f * (t0 * us2f(Wp[fw]) + t1 * us2f(Wp[fw + 1]) +
                        t2 * us2f(Wp[fw + 2]) + t3 * us2f(Wp[fw + 3]) +
                        t4 * us2f(Wp[fw + 4]) + t5 * us2f(Wp[fw + 5]) +
                        t6 * us2f(Wp[fw + 6]) + t7 * us2f(Wp[fw + 7]));
    pr += __shfl_xor(pr, 1); pr += __shfl_xor(pr, 2);
    if (lane == 0) {
      float res = pr + us2f(bp[0]);
      if (*flag) ((float*)out)[n] = res;
      else ((us16*)out)[n] = f2us(res);
    }
  }
}

extern "C" void kernel_launch(void* const* d_in, const int* in_sizes, int n_in,
                              void* d_out, int out_size, void* d_ws, size_t ws_size,
                              hipStream_t stream) {
  const int* src = (const int*)d_in[1];
  const int* dst = (const int*)d_in[2];
  char* ws = (char*)d_ws;
  int* flag   = (int*)(ws + OFF_FLAG);
  int* rowptr = (int*)(ws + OFF_ROWPTR);
  int* bsum   = (int*)(ws + OFF_BSUM);
  int* boff   = (int*)(ws + OFF_BOFF);
  int* fill   = (int*)(ws + OFF_FILL);
  int* adj    = (int*)(ws + OFF_ADJ);
  us16* fx    = (us16*)(ws + OFF_FX);
  us16* wc1   = (us16*)(ws + OFF_WC1);
  us16* wc2   = (us16*)(ws + OFF_WC2);
  us16* al1   = (us16*)(ws + OFF_PAR + 0);
  us16* ar1   = (us16*)(ws + OFF_PAR + 256);
  us16* b1    = (us16*)(ws + OFF_PAR + 512);
  us16* al2   = (us16*)(ws + OFF_PAR + 768);
  us16* ar2   = (us16*)(ws + OFF_PAR + 1024);
  us16* b2    = (us16*)(ws + OFF_PAR + 1280);
  us16* wp    = (us16*)(ws + OFF_PAR + 1536);
  us16* bp    = (us16*)(ws + OFF_PAR + 1792);
  us16* z     = (us16*)(ws + OFF_Z);
  us16* h1    = (us16*)(ws + OFF_H1);
  float* el   = (float*)(ws + OFF_EL);
  float* er   = (float*)(ws + OFF_ER);
  int* rank   = (int*)(ws + OFF_Z);  // scratch: Z region is free until k_gemm

  const int NB = (NN + 1023) / 1024;  // 49

  hipMemsetAsync(fill, 0, OFF_ADJ - OFF_FILL, stream);  // zero fill (degree counts)

  hipLaunchKernelGGL(k_detect, dim3(1), dim3(64), 0, stream, d_in[3], flag);
  hipLaunchKernelGGL(k_canon_feats, dim3(6250), dim3(256), 0, stream, d_in[0], fx, flag);
  hipLaunchKernelGGL(k_canon_small, dim3((N_SMALL + 255) / 256), dim3(256), 0, stream,
                     d_in[3], d_in[7], d_in[4], d_in[5], d_in[6],
                     d_in[8], d_in[9], d_in[10], d_in[11], d_in[12],
                     wc1, wc2, al1, ar1, b1, al2, ar2, b2, wp, bp, flag);

  // CSR: rank (atomics, coalesced rank write) -> scan(fill) -> place (no atomics)
  hipLaunchKernelGGL(k_rank, dim3(3125), dim3(256), 0, stream, dst, fill, rank);
  hipLaunchKernelGGL(k_s1, dim3(NB), dim3(1024), 0, stream, fill, bsum);
  hipLaunchKernelGGL(k_s2, dim3(1), dim3(64), 0, stream, bsum, boff, rowptr);
  hipLaunchKernelGGL(k_s3, dim3(NB), dim3(1024), 0, stream, fill, boff, rowptr);
  hipLaunchKernelGGL(k_place, dim3(3125), dim3(256), 0, stream, src, dst, rowptr, rank, adj);

  // layer 1 (gemm has fused el/er epilogue)
  hipLaunchKernelGGL(k_gemm, dim3((NN + 63) / 64), dim3(256), 0, stream, fx, wc1, z,
                     al1, ar1, el, er);
  hipLaunchKernelGGL((k_agg<1>), dim3(NN / 4), dim3(256), 0, stream, z, el, er, rowptr, adj,
                     fx, b1, h1, (us16*)nullptr, (us16*)nullptr, (void*)nullptr, flag);
  // layer 2 (+ fused head-mean and projection)
  hipLaunchKernelGGL(k_gemm, dim3((NN + 63) / 64), dim3(256), 0, stream, h1, wc2, z,
                     al2, ar2, el, er);
  hipLaunchKernelGGL((k_agg<2>), dim3(NN / 4), dim3(256), 0, stream, z, el, er, rowptr, adj,
                     h1, b2, (us16*)nullptr, wp, bp, d_out, flag);
}

// Round 10
// 254.534 us; speedup vs baseline: 1.0490x; 1.0490x over previous
//
#include <hip/hip_runtime.h>
#include <hip/hip_bf16.h>

#define NN 50000
#define NE 800000
#define HF 128

// workspace byte offsets (256-aligned), total 43,868,672 B (~41.8 MB, proven in R2)
#define OFF_FLAG   0u
#define OFF_ROWPTR 256u         // 50001 * 4 = 200004 used; region ends 200704
#define OFF_BSUM   200272u      // 49*4 bsum + pad -> fits in rowptr region slack
#define OFF_BOFF   200480u      // 49*4 boff
#define OFF_DEG    200704u      // legacy (unused)
#define OFF_FILL   400896u      // legacy (unused; fill now padded in H1 region)
#define OFF_ADJ    601088u      // 800000 * 4
#define OFF_FX     3801088u     // 6,400,000 bf16 (canonical feats)
#define OFF_WC1    16601088u    // 16384 bf16
#define OFF_WC2    16633856u    // 16384 bf16
#define OFF_PAR    16666624u    // 8 slots * 256 B: al1,ar1,b1,al2,ar2,b2,Wp,bp
#define OFF_Z      16668672u    // 6,400,000 bf16; ALSO rank[NE] scratch pre-GEMM
#define OFF_H1     29468672u    // 6,400,000 bf16; ALSO padded fill[50000*16] pre-agg1
#define OFF_EL     42268672u    // 200000 f32
#define OFF_ER     43068672u    // 200000 f32

typedef __hip_bfloat16 bf16;
typedef unsigned short us16;

#define N_SMALL 33569  // 16384+16384+6*128+32+1 elements in canon_small table

// k_prep block-range layout: rank first (long-pole atomic work starts early,
// canon copy work fills the machine behind it)
#define PREP_RANK_B   3125
#define PREP_FEATS_B  6250
#define PREP_SMALL_B  132
#define PREP_GRID     (PREP_RANK_B + PREP_FEATS_B + PREP_SMALL_B)

typedef __attribute__((ext_vector_type(8))) short bf16x8;   // MFMA A/B frag (4 VGPRs)
typedef __attribute__((ext_vector_type(4))) float f32x4;    // MFMA C/D frag

__device__ __forceinline__ float us2f(us16 u) {
  union { unsigned int i; float f; } c; c.i = ((unsigned int)u) << 16; return c.f;
}
__device__ __forceinline__ us16 f2us(float f) {
  bf16 h = __float2bfloat16(f);
  union { bf16 h; us16 u; } c; c.h = h; return c.u;
}
__device__ __forceinline__ float blo(unsigned v) {  // low bf16 of a dword
  union { unsigned i; float f; } c; c.i = v << 16; return c.f;
}
__device__ __forceinline__ float bhi(unsigned v) {  // high bf16 of a dword
  union { unsigned i; float f; } c; c.i = v & 0xffff0000u; return c.f;
}
__device__ __forceinline__ unsigned pk2(float a, float b) {
  return (unsigned)f2us(a) | ((unsigned)f2us(b) << 16);
}

// per-block dtype detection (redundant across blocks; W1's first 4KB is
// L2-broadcast). bf16 inputs: exponent field <= ~126; f32-as-ushort low
// halves are uniform -> exp >= 135 with certainty over 2048 samples.
__device__ __forceinline__ int detect_f32(const us16* __restrict__ u) {
  int t = threadIdx.x;
  int mx = 0;
  for (int i = t; i < 2048; i += 256) {
    int e = (u[i] >> 7) & 0xFF;
    mx = mx > e ? mx : e;
  }
#pragma unroll
  for (int m = 32; m >= 1; m >>= 1) {
    int o = __shfl_xor(mx, m);
    mx = mx > o ? mx : o;
  }
  __shared__ int sred[4];
  if ((t & 63) == 0) sred[t >> 6] = mx;
  __syncthreads();
  int a = sred[0] > sred[1] ? sred[0] : sred[1];
  int b = sred[2] > sred[3] ? sred[2] : sred[3];
  int r = a > b ? a : b;
  return r >= 135;
}

// ---- fused prep: rank (blocks [0,3125)) + canon_feats ([3125,9375)) +
// canon_small ([9375,9507)). Counters padded to one per 64B line.
__global__ __launch_bounds__(256) void k_prep(
    const void* __restrict__ feats, us16* __restrict__ fx,
    const void* s0, const void* s1, const void* s2, const void* s3, const void* s4,
    const void* s5, const void* s6, const void* s7, const void* s8, const void* s9,
    us16* d0, us16* d1, us16* d2, us16* d3, us16* d4,
    us16* d5, us16* d6, us16* d7, us16* d8, us16* d9,
    const int* __restrict__ dst, int* __restrict__ fillp, int* __restrict__ rank,
    int* __restrict__ flag) {
  int b = blockIdx.x;
  if (b < PREP_RANK_B) {
    int e = b * 256 + threadIdx.x;
    if (e < NE) rank[e] = atomicAdd(&fillp[dst[e] * 16], 1);
    return;
  }
  int f = detect_f32((const us16*)s0);  // s0 = W1 raw
  if (b == PREP_RANK_B && threadIdx.x == 0) *flag = f;
  if (b < PREP_RANK_B + PREP_FEATS_B) {
    int i = ((b - PREP_RANK_B) * 256 + threadIdx.x) * 4;  // < 6,400,000 exactly
    if (f) {
      float4 v = *(const float4*)((const float*)feats + i);
      ushort4 o;
      o.x = f2us(v.x); o.y = f2us(v.y); o.z = f2us(v.z); o.w = f2us(v.w);
      *(ushort4*)(fx + i) = o;
    } else {
      *(ushort4*)(fx + i) = *(const ushort4*)((const us16*)feats + i);
    }
  } else {
    const void* sp[10] = {s0, s1, s2, s3, s4, s5, s6, s7, s8, s9};
    us16* dp[10] = {d0, d1, d2, d3, d4, d5, d6, d7, d8, d9};
    const int cnt[10] = {16384, 16384, 128, 128, 128, 128, 128, 128, 32, 1};
    int gid = (b - PREP_RANK_B - PREP_FEATS_B) * 256 + threadIdx.x;
    int base = 0;
#pragma unroll
    for (int p = 0; p < 10; ++p) {
      int loc = gid - base;
      if (loc >= 0 && loc < cnt[p])
        dp[p][loc] = f ? f2us(((const float*)sp[p])[loc]) : ((const us16*)sp[p])[loc];
      base += cnt[p];
    }
  }
}

// hierarchical scan phase 1: per-block (1024 nodes) degree sums (padded reads)
__global__ __launch_bounds__(1024) void k_s1(const int* __restrict__ fillp,
                                             int* __restrict__ bsum) {
  __shared__ int red[1024];
  int t = threadIdx.x;
  int i = blockIdx.x * 1024 + t;
  red[t] = (i < NN) ? fillp[i * 16] : 0;
  __syncthreads();
  for (int s = 512; s > 0; s >>= 1) {
    if (t < s) red[t] += red[t + s];
    __syncthreads();
  }
  if (t == 0) bsum[blockIdx.x] = red[0];
}

// phase 2: one wave scans the 49 block sums -> exclusive block offsets
__global__ __launch_bounds__(64) void k_s2(const int* __restrict__ bsum,
                                           int* __restrict__ boff,
                                           int* __restrict__ rowptr) {
  int lane = threadIdx.x;
  const int NB = (NN + 1023) / 1024;  // 49
  int v = (lane < NB) ? bsum[lane] : 0;
  int orig = v;
#pragma unroll
  for (int off = 1; off < 64; off <<= 1) {
    int u = __shfl_up(v, off);
    if (lane >= off) v += u;
  }
  if (lane < NB) boff[lane] = v - orig;  // exclusive
  if (lane == 0) rowptr[NN] = NE;
}

// phase 3: per-block Hillis-Steele exclusive scan + block offset -> rowptr
__global__ __launch_bounds__(1024) void k_s3(const int* __restrict__ fillp,
                                             const int* __restrict__ boff,
                                             int* __restrict__ rowptr) {
  __shared__ int part[1024];
  int t = threadIdx.x;
  int i = blockIdx.x * 1024 + t;
  int d = (i < NN) ? fillp[i * 16] : 0;
  part[t] = d;
  __syncthreads();
  for (int off = 1; off < 1024; off <<= 1) {
    int v = (t >= off) ? part[t - off] : 0;
    __syncthreads();
    part[t] += v;
    __syncthreads();
  }
  if (i < NN) rowptr[i] = boff[blockIdx.x] + part[t] - d;
}

// atomic-free placement: adj[rowptr[d] + rank[e]] = src[e]
__global__ void k_place(const int* __restrict__ src, const int* __restrict__ dst,
                        const int* __restrict__ rowptr, const int* __restrict__ rank,
                        int* __restrict__ adj) {
  int e = blockIdx.x * 256 + threadIdx.x;
  if (e < NE) adj[rowptr[dst[e]] + rank[e]] = src[e];
}

// ---- MFMA GEMM + fused attention-coefficient epilogue.
// Z[N,128](bf16) = X[N,128](bf16) @ W[128,128](bf16); el/er[N,4](f32) from the
// f32 accumulators. 16x16x32 bf16 MFMA; 4 waves x 16 rows x 128 cols per block.
// W repacked into LDS in B-fragment order (one ds_read_b128 per (ntile,kstep)).
// Fragment maps (m89/m120-verified): A[m=lane&15][k=q*8+j], B[k=q*8+j][n=lane&15],
// D row=q*4+reg, col=t*16+c.
__global__ __launch_bounds__(256) void k_gemm(const us16* __restrict__ X,
                                              const us16* __restrict__ W,
                                              us16* __restrict__ Z,
                                              const us16* __restrict__ al,
                                              const us16* __restrict__ ar,
                                              float* __restrict__ el,
                                              float* __restrict__ er) {
  __shared__ us16 Wl[HF * HF];
  int tid = threadIdx.x;
  for (int e = tid; e < HF * HF; e += 256) {
    int k = e >> 7, n = e & 127;
    int d = ((((k >> 5) * 8 + (n >> 4)) * 4 + ((k >> 3) & 3)) * 16 + (n & 15)) * 8 + (k & 7);
    Wl[d] = W[e];
  }
  __syncthreads();

  int w = tid >> 6;        // wave 0..3
  int lane = tid & 63;
  int q = lane >> 4;       // quad 0..3
  int c = lane & 15;       // col-in-tile / row-in-tile
  int m0 = blockIdx.x * 64 + w * 16;

  int rA = m0 + c;                       // A-frag row for this lane
  if (rA >= NN) rA = NN - 1;             // clamp (stores are guarded)
  const us16* xrow = X + (size_t)rA * HF;

  f32x4 acc[8] = {};
#pragma unroll
  for (int s = 0; s < 4; ++s) {
    bf16x8 a = *(const bf16x8*)&xrow[s * 32 + q * 8];
#pragma unroll
    for (int t = 0; t < 8; ++t) {
      bf16x8 b = *(const bf16x8*)&Wl[((((s * 8) + t) * 4 + q) * 16 + c) * 8];
      acc[t] = __builtin_amdgcn_mfma_f32_16x16x32_bf16(a, b, acc[t], 0, 0, 0);
    }
  }

  // Z store
#pragma unroll
  for (int reg = 0; reg < 4; ++reg) {
    int row = m0 + q * 4 + reg;
    if (row < NN) {
      us16* zrow = Z + (size_t)row * HF;
#pragma unroll
      for (int t = 0; t < 8; ++t) zrow[t * 16 + c] = f2us(acc[t][reg]);
    }
  }

  // fused coef epilogue
  float alv[8], arv[8];
#pragma unroll
  for (int t = 0; t < 8; ++t) {
    alv[t] = us2f(al[t * 16 + c]);
    arv[t] = us2f(ar[t * 16 + c]);
  }
#pragma unroll
  for (int reg = 0; reg < 4; ++reg) {
    int row = m0 + q * 4 + reg;
    float pl[4], pr[4];
#pragma unroll
    for (int h = 0; h < 4; ++h) {
      pl[h] = acc[2 * h][reg] * alv[2 * h] + acc[2 * h + 1][reg] * alv[2 * h + 1];
      pr[h] = acc[2 * h][reg] * arv[2 * h] + acc[2 * h + 1][reg] * arv[2 * h + 1];
    }
#pragma unroll
    for (int m = 1; m < 16; m <<= 1) {
#pragma unroll
      for (int h = 0; h < 4; ++h) {
        pl[h] += __shfl_xor(pl[h], m);
        pr[h] += __shfl_xor(pr[h], m);
      }
    }
    if (row < NN) {
      int cc = c & 3;
      float vl = cc == 0 ? pl[0] : cc == 1 ? pl[1] : cc == 2 ? pl[2] : pl[3];
      float vr = cc == 0 ? pr[0] : cc == 1 ? pr[1] : cc == 2 ? pr[2] : pr[3];
      if (c < 4) el[row * 4 + cc] = vl;
      else if (c < 8) er[row * 4 + cc] = vr;
    }
  }
}

// One wave per destination node; 4 nodes per 256-thread block (no barriers).
// Wave layout: 4 edge-groups (g=lane>>4) x 16 feature-lanes (p=lane&15).
// Each lane owns 8 features f0=p*8 (one uint4 = 16B load), head hl=p>>2.
// No max pass (scores O(+-10), exp can't overflow f32; softmax shift-invariant).
// 2-wide unroll (R8 form; R9's 4-wide measured neutral-negative).
template <int LAYER>
__global__ __launch_bounds__(256) void k_agg(
    const us16* __restrict__ Z, const float* __restrict__ el,
    const float* __restrict__ er, const int* __restrict__ rowptr,
    const int* __restrict__ adj, const us16* __restrict__ resid,
    const us16* __restrict__ bias, us16* __restrict__ Hout,
    const us16* __restrict__ Wp, const us16* __restrict__ bp,
    void* __restrict__ out, const int* __restrict__ flag) {
  int n = blockIdx.x * 4 + (threadIdx.x >> 6);  // NN = 50000 = 12500*4 exact
  int lane = threadIdx.x & 63;
  int g = lane >> 4;   // edge group 0..3
  int p = lane & 15;   // feature position 0..15
  int hl = p >> 2;     // head owning this lane's features
  int f0 = p * 8;      // first of 8 features
  int begin = rowptr[n];
  int deg = rowptr[n + 1] - begin;
  float erh = er[n * 4 + hl];

  float acc[8] = {};
  float ssum = 0.f;
  int i = g;
  for (; i + 4 < deg; i += 8) {  // 2 edges per group-iteration, loads paired
    int s0 = adj[begin + i];
    int s1 = adj[begin + i + 4];
    float l0 = el[s0 * 4 + hl];
    float l1 = el[s1 * 4 + hl];
    uint4 za = *(const uint4*)&Z[(size_t)s0 * HF + f0];
    uint4 zb = *(const uint4*)&Z[(size_t)s1 * HF + f0];
    float sc0 = l0 + erh; sc0 = sc0 > 0.f ? sc0 : 0.2f * sc0;
    float sc1 = l1 + erh; sc1 = sc1 > 0.f ? sc1 : 0.2f * sc1;
    float ex0 = __expf(sc0);
    float ex1 = __expf(sc1);
    ssum += ex0 + ex1;
    acc[0] = fmaf(ex0, blo(za.x), acc[0]); acc[1] = fmaf(ex0, bhi(za.x), acc[1]);
    acc[2] = fmaf(ex0, blo(za.y), acc[2]); acc[3] = fmaf(ex0, bhi(za.y), acc[3]);
    acc[4] = fmaf(ex0, blo(za.z), acc[4]); acc[5] = fmaf(ex0, bhi(za.z), acc[5]);
    acc[6] = fmaf(ex0, blo(za.w), acc[6]); acc[7] = fmaf(ex0, bhi(za.w), acc[7]);
    acc[0] = fmaf(ex1, blo(zb.x), acc[0]); acc[1] = fmaf(ex1, bhi(zb.x), acc[1]);
    acc[2] = fmaf(ex1, blo(zb.y), acc[2]); acc[3] = fmaf(ex1, bhi(zb.y), acc[3]);
    acc[4] = fmaf(ex1, blo(zb.z), acc[4]); acc[5] = fmaf(ex1, bhi(zb.z), acc[5]);
    acc[6] = fmaf(ex1, blo(zb.w), acc[6]); acc[7] = fmaf(ex1, bhi(zb.w), acc[7]);
  }
  if (i < deg) {  // tail edge for this group
    int s = adj[begin + i];
    float sc = el[s * 4 + hl] + erh;
    sc = sc > 0.f ? sc : 0.2f * sc;
    float ex = __expf(sc);
    ssum += ex;
    uint4 zq = *(const uint4*)&Z[(size_t)s * HF + f0];
    acc[0] = fmaf(ex, blo(zq.x), acc[0]); acc[1] = fmaf(ex, bhi(zq.x), acc[1]);
    acc[2] = fmaf(ex, blo(zq.y), acc[2]); acc[3] = fmaf(ex, bhi(zq.y), acc[3]);
    acc[4] = fmaf(ex, blo(zq.z), acc[4]); acc[5] = fmaf(ex, bhi(zq.z), acc[5]);
    acc[6] = fmaf(ex, blo(zq.w), acc[6]); acc[7] = fmaf(ex, bhi(zq.w), acc[7]);
  }
  // combine the 4 edge-groups (lanes l, l^16, l^32, l^48 share p -> same feats/head)
  ssum += __shfl_xor(ssum, 16); ssum += __shfl_xor(ssum, 32);
#pragma unroll
  for (int j = 0; j < 8; ++j) {
    acc[j] += __shfl_xor(acc[j], 16);
    acc[j] += __shfl_xor(acc[j], 32);
  }
  float inv = 1.f / fmaxf(ssum, 1e-9f);  // deg==0 -> acc==0 -> r==0 (matches ref)

  uint4 xq = *(const uint4*)&resid[(size_t)n * HF + f0];
  uint4 bq = *(const uint4*)&bias[f0];
  float t0 = fmaf(acc[0], inv, blo(xq.x) + blo(bq.x));
  float t1 = fmaf(acc[1], inv, bhi(xq.x) + bhi(bq.x));
  float t2 = fmaf(acc[2], inv, blo(xq.y) + blo(bq.y));
  float t3 = fmaf(acc[3], inv, bhi(xq.y) + bhi(bq.y));
  float t4 = fmaf(acc[4], inv, blo(xq.z) + blo(bq.z));
  float t5 = fmaf(acc[5], inv, bhi(xq.z) + bhi(bq.z));
  float t6 = fmaf(acc[6], inv, blo(xq.w) + blo(bq.w));
  float t7 = fmaf(acc[7], inv, bhi(xq.w) + bhi(bq.w));

  if (LAYER == 1) {
    t0 = t0 > 0.f ? t0 : __expf(t0) - 1.f;  // ELU
    t1 = t1 > 0.f ? t1 : __expf(t1) - 1.f;
    t2 = t2 > 0.f ? t2 : __expf(t2) - 1.f;
    t3 = t3 > 0.f ? t3 : __expf(t3) - 1.f;
    t4 = t4 > 0.f ? t4 : __expf(t4) - 1.f;
    t5 = t5 > 0.f ? t5 : __expf(t5) - 1.f;
    t6 = t6 > 0.f ? t6 : __expf(t6) - 1.f;
    t7 = t7 > 0.f ? t7 : __expf(t7) - 1.f;
    if (g == 0) {
      uint4 o;
      o.x = pk2(t0, t1); o.y = pk2(t2, t3); o.z = pk2(t4, t5); o.w = pk2(t6, t7);
      *(uint4*)&Hout[(size_t)n * HF + f0] = o;
    }
  } else {
    // mean over heads: lanes {p, p^4, p^8, p^12} hold same within-head feats
    t0 += __shfl_xor(t0, 4); t0 += __shfl_xor(t0, 8);
    t1 += __shfl_xor(t1, 4); t1 += __shfl_xor(t1, 8);
    t2 += __shfl_xor(t2, 4); t2 += __shfl_xor(t2, 8);
    t3 += __shfl_xor(t3, 4); t3 += __shfl_xor(t3, 8);
    t4 += __shfl_xor(t4, 4); t4 += __shfl_xor(t4, 8);
    t5 += __shfl_xor(t5, 4); t5 += __shfl_xor(t5, 8);
    t6 += __shfl_xor(t6, 4); t6 += __shfl_xor(t6, 8);
    t7 += __shfl_xor(t7, 4); t7 += __shfl_xor(t7, 8);
    // projection over the 32 mean features: lane p&3 holds feats (p&3)*8..+7
    int fw = (p & 3) * 8;
    float pr = 0.25f * (t0 * us2f(Wp[fw]) + t1 * us2f(Wp[fw + 1]) +
                        t2 * us2f(Wp[fw + 2]) + t3 * us2f(Wp[fw + 3]) +
                        t4 * us2f(Wp[fw + 4]) + t5 * us2f(Wp[fw + 5]) +
                        t6 * us2f(Wp[fw + 6]) + t7 * us2f(Wp[fw + 7]));
    pr += __shfl_xor(pr, 1); pr += __shfl_xor(pr, 2);
    if (lane == 0) {
      float res = pr + us2f(bp[0]);
      if (*flag) ((float*)out)[n] = res;
      else ((us16*)out)[n] = f2us(res);
    }
  }
}

extern "C" void kernel_launch(void* const* d_in, const int* in_sizes, int n_in,
                              void* d_out, int out_size, void* d_ws, size_t ws_size,
                              hipStream_t stream) {
  const int* src = (const int*)d_in[1];
  const int* dst = (const int*)d_in[2];
  char* ws = (char*)d_ws;
  int* flag   = (int*)(ws + OFF_FLAG);
  int* rowptr = (int*)(ws + OFF_ROWPTR);
  int* bsum   = (int*)(ws + OFF_BSUM);
  int* boff   = (int*)(ws + OFF_BOFF);
  int* adj    = (int*)(ws + OFF_ADJ);
  us16* fx    = (us16*)(ws + OFF_FX);
  us16* wc1   = (us16*)(ws + OFF_WC1);
  us16* wc2   = (us16*)(ws + OFF_WC2);
  us16* al1   = (us16*)(ws + OFF_PAR + 0);
  us16* ar1   = (us16*)(ws + OFF_PAR + 256);
  us16* b1    = (us16*)(ws + OFF_PAR + 512);
  us16* al2   = (us16*)(ws + OFF_PAR + 768);
  us16* ar2   = (us16*)(ws + OFF_PAR + 1024);
  us16* b2    = (us16*)(ws + OFF_PAR + 1280);
  us16* wp    = (us16*)(ws + OFF_PAR + 1536);
  us16* bp    = (us16*)(ws + OFF_PAR + 1792);
  us16* z     = (us16*)(ws + OFF_Z);
  us16* h1    = (us16*)(ws + OFF_H1);
  float* el   = (float*)(ws + OFF_EL);
  float* er   = (float*)(ws + OFF_ER);
  int* rank   = (int*)(ws + OFF_Z);   // scratch: Z region free until k_gemm L1
  int* fillp  = (int*)(ws + OFF_H1);  // padded counters: H1 region free until k_agg L1

  const int NB = (NN + 1023) / 1024;  // 49

  hipMemsetAsync(fillp, 0, (size_t)NN * 16 * 4, stream);  // zero padded counters

  // fused prep: rank (atomics, padded lines) overlapped with canon copies
  hipLaunchKernelGGL(k_prep, dim3(PREP_GRID), dim3(256), 0, stream,
                     d_in[0], fx,
                     d_in[3], d_in[7], d_in[4], d_in[5], d_in[6],
                     d_in[8], d_in[9], d_in[10], d_in[11], d_in[12],
                     wc1, wc2, al1, ar1, b1, al2, ar2, b2, wp, bp,
                     dst, fillp, rank, flag);

  hipLaunchKernelGGL(k_s1, dim3(NB), dim3(1024), 0, stream, fillp, bsum);
  hipLaunchKernelGGL(k_s2, dim3(1), dim3(64), 0, stream, bsum, boff, rowptr);
  hipLaunchKernelGGL(k_s3, dim3(NB), dim3(1024), 0, stream, fillp, boff, rowptr);
  hipLaunchKernelGGL(k_place, dim3(3125), dim3(256), 0, stream, src, dst, rowptr, rank, adj);

  // layer 1 (gemm has fused el/er epilogue)
  hipLaunchKernelGGL(k_gemm, dim3((NN + 63) / 64), dim3(256), 0, stream, fx, wc1, z,
                     al1, ar1, el, er);
  hipLaunchKernelGGL((k_agg<1>), dim3(NN / 4), dim3(256), 0, stream, z, el, er, rowptr, adj,
                     fx, b1, h1, (us16*)nullptr, (us16*)nullptr, (void*)nullptr, flag);
  // layer 2 (+ fused head-mean and projection)
  hipLaunchKernelGGL(k_gemm, dim3((NN + 63) / 64), dim3(256), 0, stream, h1, wc2, z,
                     al2, ar2, el, er);
  hipLaunchKernelGGL((k_agg<2>), dim3(NN / 4), dim3(256), 0, stream, z, el, er, rowptr, adj,
                     h1, b2, (us16*)nullptr, wp, bp, d_out, flag);
}

// Round 11
// 250.667 us; speedup vs baseline: 1.0652x; 1.0154x over previous
//
#include <hip/hip_runtime.h>
#include <hip/hip_bf16.h>

#define NN 50000
#define NE 800000
#define HF 128

// workspace byte offsets (256-aligned); ws_size = 256 MiB (observed poison fill)
#define OFF_FLAG   0u
#define OFF_ROWPTR 256u         // 50001 * 4 = 200004 used; region ends 200704
#define OFF_BSUM   200272u      // 49*4
#define OFF_BOFF   200480u      // 49*4
#define OFF_SYNC   200680u      // 2 ints (scanall barrier), zeroed by k_prep
#define OFF_ADJ    601088u      // 800000 * 4
#define OFF_FX     3801088u     // 6,400,000 bf16 (canonical feats)
#define OFF_WC1    16601088u    // 16384 bf16
#define OFF_WC2    16633856u    // 16384 bf16
#define OFF_PAR    16666624u    // 8 slots * 256 B: al1,ar1,b1,al2,ar2,b2,Wp,bp
#define OFF_Z      16668672u    // 6,400,000 bf16
#define OFF_H1     29468672u    // 6,400,000 bf16; ALSO padded fill[50000*16] pre-agg1
#define OFF_EL     42268672u    // 200000 f32
#define OFF_ER     43068672u    // 200000 f32
#define OFF_RANK   50000128u    // 800000 * 4 (own region; ws is 256 MiB)

typedef __hip_bfloat16 bf16;
typedef unsigned short us16;

// k_prep block-range layout: rank first (atomic long-pole starts early)
#define PREP_RANK_B   3125
#define PREP_FEATS_B  6250
#define PREP_SMALL_B  132
#define PREP_GRID     (PREP_RANK_B + PREP_FEATS_B + PREP_SMALL_B)

#define NB_SCAN 49       // (NN + 1023) / 1024
#define GP_PLACE_B 3125  // place blocks in k_gemmplace
#define GEMM_B 782       // (NN + 63) / 64

typedef __attribute__((ext_vector_type(8))) short bf16x8;   // MFMA A/B frag
typedef __attribute__((ext_vector_type(4))) float f32x4;    // MFMA C/D frag

__device__ __forceinline__ float us2f(us16 u) {
  union { unsigned int i; float f; } c; c.i = ((unsigned int)u) << 16; return c.f;
}
__device__ __forceinline__ us16 f2us(float f) {
  bf16 h = __float2bfloat16(f);
  union { bf16 h; us16 u; } c; c.h = h; return c.u;
}
__device__ __forceinline__ float blo(unsigned v) {
  union { unsigned i; float f; } c; c.i = v << 16; return c.f;
}
__device__ __forceinline__ float bhi(unsigned v) {
  union { unsigned i; float f; } c; c.i = v & 0xffff0000u; return c.f;
}
__device__ __forceinline__ unsigned pk2(float a, float b) {
  return (unsigned)f2us(a) | ((unsigned)f2us(b) << 16);
}

// per-block dtype detection (W1's first 4KB, L2-broadcast)
__device__ __forceinline__ int detect_f32(const us16* __restrict__ u) {
  int t = threadIdx.x;
  int mx = 0;
  for (int i = t; i < 2048; i += 256) {
    int e = (u[i] >> 7) & 0xFF;
    mx = mx > e ? mx : e;
  }
#pragma unroll
  for (int m = 32; m >= 1; m >>= 1) {
    int o = __shfl_xor(mx, m);
    mx = mx > o ? mx : o;
  }
  __shared__ int sred[4];
  if ((t & 63) == 0) sred[t >> 6] = mx;
  __syncthreads();
  int a = sred[0] > sred[1] ? sred[0] : sred[1];
  int b = sred[2] > sred[3] ? sred[2] : sred[3];
  int r = a > b ? a : b;
  return r >= 135;
}

// ---- fused prep: rank + canon_feats + canon_small; zeroes scanall sync vars.
__global__ __launch_bounds__(256) void k_prep(
    const void* __restrict__ feats, us16* __restrict__ fx,
    const void* s0, const void* s1, const void* s2, const void* s3, const void* s4,
    const void* s5, const void* s6, const void* s7, const void* s8, const void* s9,
    us16* d0, us16* d1, us16* d2, us16* d3, us16* d4,
    us16* d5, us16* d6, us16* d7, us16* d8, us16* d9,
    const int* __restrict__ dst, int* __restrict__ fillp, int* __restrict__ rank,
    int* __restrict__ flag, int* __restrict__ sync) {
  int b = blockIdx.x;
  if (b == 0 && threadIdx.x == 0) { sync[0] = 0; sync[1] = 0; }
  if (b < PREP_RANK_B) {
    int e = b * 256 + threadIdx.x;
    if (e < NE) rank[e] = atomicAdd(&fillp[dst[e] * 16], 1);
    return;
  }
  int f = detect_f32((const us16*)s0);  // s0 = W1 raw
  if (b == PREP_RANK_B && threadIdx.x == 0) *flag = f;
  if (b < PREP_RANK_B + PREP_FEATS_B) {
    int i = ((b - PREP_RANK_B) * 256 + threadIdx.x) * 4;  // < 6,400,000 exactly
    if (f) {
      float4 v = *(const float4*)((const float*)feats + i);
      ushort4 o;
      o.x = f2us(v.x); o.y = f2us(v.y); o.z = f2us(v.z); o.w = f2us(v.w);
      *(ushort4*)(fx + i) = o;
    } else {
      *(ushort4*)(fx + i) = *(const ushort4*)((const us16*)feats + i);
    }
  } else {
    const void* sp[10] = {s0, s1, s2, s3, s4, s5, s6, s7, s8, s9};
    us16* dp[10] = {d0, d1, d2, d3, d4, d5, d6, d7, d8, d9};
    const int cnt[10] = {16384, 16384, 128, 128, 128, 128, 128, 128, 32, 1};
    int gid = (b - PREP_RANK_B - PREP_FEATS_B) * 256 + threadIdx.x;
    int base = 0;
#pragma unroll
    for (int p = 0; p < 10; ++p) {
      int loc = gid - base;
      if (loc >= 0 && loc < cnt[p])
        dp[p][loc] = f ? f2us(((const float*)sp[p])[loc]) : ((const us16*)sp[p])[loc];
      base += cnt[p];
    }
  }
}

// ---- fused hierarchical scan (s1+s2+s3) in ONE dispatch. 49 blocks, all
// co-resident; device-scope atomic arrive counter + release flag barrier.
__global__ __launch_bounds__(1024) void k_scanall(const int* __restrict__ fillp,
                                                  int* __restrict__ bsum,
                                                  int* __restrict__ boff,
                                                  int* __restrict__ rowptr,
                                                  int* __restrict__ sync) {
  __shared__ int part[1024];
  int t = threadIdx.x, b = blockIdx.x;
  int i = b * 1024 + t;
  int d = (i < NN) ? fillp[i * 16] : 0;
  part[t] = d;
  __syncthreads();
  for (int off = 1; off < 1024; off <<= 1) {
    int v = (t >= off) ? part[t - off] : 0;
    __syncthreads();
    part[t] += v;
    __syncthreads();
  }
  int incl = part[t];  // inclusive within-block prefix
  if (t == 1023) {
    bsum[b] = incl;
    __threadfence();
    atomicAdd(&sync[0], 1);  // arrive
  }
  if (b == 0) {
    __syncthreads();
    if (t == 0) {
      while (atomicAdd(&sync[0], 0) < NB_SCAN) { }
    }
    __syncthreads();
    if (t < 64) {
      int v = (t < NB_SCAN) ? bsum[t] : 0;
      int orig = v;
#pragma unroll
      for (int off = 1; off < 64; off <<= 1) {
        int u = __shfl_up(v, off);
        if (t >= off) v += u;
      }
      if (t < NB_SCAN) boff[t] = v - orig;  // exclusive block offsets
      if (t == 0) rowptr[NN] = NE;
    }
    __syncthreads();
    if (t == 0) {
      __threadfence();
      atomicExch(&sync[1], 1);  // release
    }
  }
  if (t == 0) {
    while (atomicAdd(&sync[1], 0) == 0) { }
  }
  __syncthreads();
  if (i < NN) rowptr[i] = boff[b] + incl - d;
}

// ---- MFMA GEMM body + fused el/er epilogue (shared by L1-fused and L2 kernels)
__device__ __forceinline__ void gemm_body(const us16* __restrict__ X,
                                          const us16* __restrict__ W,
                                          us16* __restrict__ Z,
                                          const us16* __restrict__ al,
                                          const us16* __restrict__ ar,
                                          float* __restrict__ el,
                                          float* __restrict__ er, int blk) {
  __shared__ us16 Wl[HF * HF];
  int tid = threadIdx.x;
  for (int e = tid; e < HF * HF; e += 256) {
    int k = e >> 7, n = e & 127;
    int d = ((((k >> 5) * 8 + (n >> 4)) * 4 + ((k >> 3) & 3)) * 16 + (n & 15)) * 8 + (k & 7);
    Wl[d] = W[e];
  }
  __syncthreads();

  int w = tid >> 6;
  int lane = tid & 63;
  int q = lane >> 4;
  int c = lane & 15;
  int m0 = blk * 64 + w * 16;

  int rA = m0 + c;
  if (rA >= NN) rA = NN - 1;
  const us16* xrow = X + (size_t)rA * HF;

  f32x4 acc[8] = {};
#pragma unroll
  for (int s = 0; s < 4; ++s) {
    bf16x8 a = *(const bf16x8*)&xrow[s * 32 + q * 8];
#pragma unroll
    for (int t = 0; t < 8; ++t) {
      bf16x8 bb = *(const bf16x8*)&Wl[((((s * 8) + t) * 4 + q) * 16 + c) * 8];
      acc[t] = __builtin_amdgcn_mfma_f32_16x16x32_bf16(a, bb, acc[t], 0, 0, 0);
    }
  }

#pragma unroll
  for (int reg = 0; reg < 4; ++reg) {
    int row = m0 + q * 4 + reg;
    if (row < NN) {
      us16* zrow = Z + (size_t)row * HF;
#pragma unroll
      for (int t = 0; t < 8; ++t) zrow[t * 16 + c] = f2us(acc[t][reg]);
    }
  }

  float alv[8], arv[8];
#pragma unroll
  for (int t = 0; t < 8; ++t) {
    alv[t] = us2f(al[t * 16 + c]);
    arv[t] = us2f(ar[t * 16 + c]);
  }
#pragma unroll
  for (int reg = 0; reg < 4; ++reg) {
    int row = m0 + q * 4 + reg;
    float pl[4], pr[4];
#pragma unroll
    for (int h = 0; h < 4; ++h) {
      pl[h] = acc[2 * h][reg] * alv[2 * h] + acc[2 * h + 1][reg] * alv[2 * h + 1];
      pr[h] = acc[2 * h][reg] * arv[2 * h] + acc[2 * h + 1][reg] * arv[2 * h + 1];
    }
#pragma unroll
    for (int m = 1; m < 16; m <<= 1) {
#pragma unroll
      for (int h = 0; h < 4; ++h) {
        pl[h] += __shfl_xor(pl[h], m);
        pr[h] += __shfl_xor(pr[h], m);
      }
    }
    if (row < NN) {
      int cc = c & 3;
      float vl = cc == 0 ? pl[0] : cc == 1 ? pl[1] : cc == 2 ? pl[2] : pl[3];
      float vr = cc == 0 ? pr[0] : cc == 1 ? pr[1] : cc == 2 ? pr[2] : pr[3];
      if (c < 4) el[row * 4 + cc] = vl;
      else if (c < 8) er[row * 4 + cc] = vr;
    }
  }
}

// fused: place (blocks [0,3125), latency/write-bound) + gemm L1 (blocks
// [3125,3907), compute-bound) — overlapping complementary pipes.
__global__ __launch_bounds__(256) void k_gemmplace(
    const us16* __restrict__ X, const us16* __restrict__ W, us16* __restrict__ Z,
    const us16* __restrict__ al, const us16* __restrict__ ar,
    float* __restrict__ el, float* __restrict__ er,
    const int* __restrict__ src, const int* __restrict__ dst,
    const int* __restrict__ rowptr, const int* __restrict__ rank,
    int* __restrict__ adj) {
  int b = blockIdx.x;
  if (b < GP_PLACE_B) {
    int e = b * 256 + threadIdx.x;
    if (e < NE) adj[rowptr[dst[e]] + rank[e]] = src[e];
    return;
  }
  gemm_body(X, W, Z, al, ar, el, er, b - GP_PLACE_B);
}

__global__ __launch_bounds__(256) void k_gemm(const us16* __restrict__ X,
                                              const us16* __restrict__ W,
                                              us16* __restrict__ Z,
                                              const us16* __restrict__ al,
                                              const us16* __restrict__ ar,
                                              float* __restrict__ el,
                                              float* __restrict__ er) {
  gemm_body(X, W, Z, al, ar, el, er, blockIdx.x);
}

// One wave per destination node; 4 nodes per 256-thread block (no barriers).
// 2-wide unroll (R8 form; R9's 4-wide measured neutral-negative).
template <int LAYER>
__global__ __launch_bounds__(256) void k_agg(
    const us16* __restrict__ Z, const float* __restrict__ el,
    const float* __restrict__ er, const int* __restrict__ rowptr,
    const int* __restrict__ adj, const us16* __restrict__ resid,
    const us16* __restrict__ bias, us16* __restrict__ Hout,
    const us16* __restrict__ Wp, const us16* __restrict__ bp,
    void* __restrict__ out, const int* __restrict__ flag) {
  int n = blockIdx.x * 4 + (threadIdx.x >> 6);
  int lane = threadIdx.x & 63;
  int g = lane >> 4;
  int p = lane & 15;
  int hl = p >> 2;
  int f0 = p * 8;
  int begin = rowptr[n];
  int deg = rowptr[n + 1] - begin;
  float erh = er[n * 4 + hl];

  float acc[8] = {};
  float ssum = 0.f;
  int i = g;
  for (; i + 4 < deg; i += 8) {
    int s0 = adj[begin + i];
    int s1 = adj[begin + i + 4];
    float l0 = el[s0 * 4 + hl];
    float l1 = el[s1 * 4 + hl];
    uint4 za = *(const uint4*)&Z[(size_t)s0 * HF + f0];
    uint4 zb = *(const uint4*)&Z[(size_t)s1 * HF + f0];
    float sc0 = l0 + erh; sc0 = sc0 > 0.f ? sc0 : 0.2f * sc0;
    float sc1 = l1 + erh; sc1 = sc1 > 0.f ? sc1 : 0.2f * sc1;
    float ex0 = __expf(sc0);
    float ex1 = __expf(sc1);
    ssum += ex0 + ex1;
    acc[0] = fmaf(ex0, blo(za.x), acc[0]); acc[1] = fmaf(ex0, bhi(za.x), acc[1]);
    acc[2] = fmaf(ex0, blo(za.y), acc[2]); acc[3] = fmaf(ex0, bhi(za.y), acc[3]);
    acc[4] = fmaf(ex0, blo(za.z), acc[4]); acc[5] = fmaf(ex0, bhi(za.z), acc[5]);
    acc[6] = fmaf(ex0, blo(za.w), acc[6]); acc[7] = fmaf(ex0, bhi(za.w), acc[7]);
    acc[0] = fmaf(ex1, blo(zb.x), acc[0]); acc[1] = fmaf(ex1, bhi(zb.x), acc[1]);
    acc[2] = fmaf(ex1, blo(zb.y), acc[2]); acc[3] = fmaf(ex1, bhi(zb.y), acc[3]);
    acc[4] = fmaf(ex1, blo(zb.z), acc[4]); acc[5] = fmaf(ex1, bhi(zb.z), acc[5]);
    acc[6] = fmaf(ex1, blo(zb.w), acc[6]); acc[7] = fmaf(ex1, bhi(zb.w), acc[7]);
  }
  if (i < deg) {
    int s = adj[begin + i];
    float sc = el[s * 4 + hl] + erh;
    sc = sc > 0.f ? sc : 0.2f * sc;
    float ex = __expf(sc);
    ssum += ex;
    uint4 zq = *(const uint4*)&Z[(size_t)s * HF + f0];
    acc[0] = fmaf(ex, blo(zq.x), acc[0]); acc[1] = fmaf(ex, bhi(zq.x), acc[1]);
    acc[2] = fmaf(ex, blo(zq.y), acc[2]); acc[3] = fmaf(ex, bhi(zq.y), acc[3]);
    acc[4] = fmaf(ex, blo(zq.z), acc[4]); acc[5] = fmaf(ex, bhi(zq.z), acc[5]);
    acc[6] = fmaf(ex, blo(zq.w), acc[6]); acc[7] = fmaf(ex, bhi(zq.w), acc[7]);
  }
  ssum += __shfl_xor(ssum, 16); ssum += __shfl_xor(ssum, 32);
#pragma unroll
  for (int j = 0; j < 8; ++j) {
    acc[j] += __shfl_xor(acc[j], 16);
    acc[j] += __shfl_xor(acc[j], 32);
  }
  float inv = 1.f / fmaxf(ssum, 1e-9f);

  uint4 xq = *(const uint4*)&resid[(size_t)n * HF + f0];
  uint4 bq = *(const uint4*)&bias[f0];
  float t0 = fmaf(acc[0], inv, blo(xq.x) + blo(bq.x));
  float t1 = fmaf(acc[1], inv, bhi(xq.x) + bhi(bq.x));
  float t2 = fmaf(acc[2], inv, blo(xq.y) + blo(bq.y));
  float t3 = fmaf(acc[3], inv, bhi(xq.y) + bhi(bq.y));
  float t4 = fmaf(acc[4], inv, blo(xq.z) + blo(bq.z));
  float t5 = fmaf(acc[5], inv, bhi(xq.z) + bhi(bq.z));
  float t6 = fmaf(acc[6], inv, blo(xq.w) + blo(bq.w));
  float t7 = fmaf(acc[7], inv, bhi(xq.w) + bhi(bq.w));

  if (LAYER == 1) {
    t0 = t0 > 0.f ? t0 : __expf(t0) - 1.f;
    t1 = t1 > 0.f ? t1 : __expf(t1) - 1.f;
    t2 = t2 > 0.f ? t2 : __expf(t2) - 1.f;
    t3 = t3 > 0.f ? t3 : __expf(t3) - 1.f;
    t4 = t4 > 0.f ? t4 : __expf(t4) - 1.f;
    t5 = t5 > 0.f ? t5 : __expf(t5) - 1.f;
    t6 = t6 > 0.f ? t6 : __expf(t6) - 1.f;
    t7 = t7 > 0.f ? t7 : __expf(t7) - 1.f;
    if (g == 0) {
      uint4 o;
      o.x = pk2(t0, t1); o.y = pk2(t2, t3); o.z = pk2(t4, t5); o.w = pk2(t6, t7);
      *(uint4*)&Hout[(size_t)n * HF + f0] = o;
    }
  } else {
    t0 += __shfl_xor(t0, 4); t0 += __shfl_xor(t0, 8);
    t1 += __shfl_xor(t1, 4); t1 += __shfl_xor(t1, 8);
    t2 += __shfl_xor(t2, 4); t2 += __shfl_xor(t2, 8);
    t3 += __shfl_xor(t3, 4); t3 += __shfl_xor(t3, 8);
    t4 += __shfl_xor(t4, 4); t4 += __shfl_xor(t4, 8);
    t5 += __shfl_xor(t5, 4); t5 += __shfl_xor(t5, 8);
    t6 += __shfl_xor(t6, 4); t6 += __shfl_xor(t6, 8);
    t7 += __shfl_xor(t7, 4); t7 += __shfl_xor(t7, 8);
    int fw = (p & 3) * 8;
    float pr = 0.25f * (t0 * us2f(Wp[fw]) + t1 * us2f(Wp[fw + 1]) +
                        t2 * us2f(Wp[fw + 2]) + t3 * us2f(Wp[fw + 3]) +
                        t4 * us2f(Wp[fw + 4]) + t5 * us2f(Wp[fw + 5]) +
                        t6 * us2f(Wp[fw + 6]) + t7 * us2f(Wp[fw + 7]));
    pr += __shfl_xor(pr, 1); pr += __shfl_xor(pr, 2);
    if (lane == 0) {
      float res = pr + us2f(bp[0]);
      if (*flag) ((float*)out)[n] = res;
      else ((us16*)out)[n] = f2us(res);
    }
  }
}

extern "C" void kernel_launch(void* const* d_in, const int* in_sizes, int n_in,
                              void* d_out, int out_size, void* d_ws, size_t ws_size,
                              hipStream_t stream) {
  const int* src = (const int*)d_in[1];
  const int* dst = (const int*)d_in[2];
  char* ws = (char*)d_ws;
  int* flag   = (int*)(ws + OFF_FLAG);
  int* rowptr = (int*)(ws + OFF_ROWPTR);
  int* bsum   = (int*)(ws + OFF_BSUM);
  int* boff   = (int*)(ws + OFF_BOFF);
  int* sync   = (int*)(ws + OFF_SYNC);
  int* adj    = (int*)(ws + OFF_ADJ);
  us16* fx    = (us16*)(ws + OFF_FX);
  us16* wc1   = (us16*)(ws + OFF_WC1);
  us16* wc2   = (us16*)(ws + OFF_WC2);
  us16* al1   = (us16*)(ws + OFF_PAR + 0);
  us16* ar1   = (us16*)(ws + OFF_PAR + 256);
  us16* b1    = (us16*)(ws + OFF_PAR + 512);
  us16* al2   = (us16*)(ws + OFF_PAR + 768);
  us16* ar2   = (us16*)(ws + OFF_PAR + 1024);
  us16* b2    = (us16*)(ws + OFF_PAR + 1280);
  us16* wp    = (us16*)(ws + OFF_PAR + 1536);
  us16* bp    = (us16*)(ws + OFF_PAR + 1792);
  us16* z     = (us16*)(ws + OFF_Z);
  us16* h1    = (us16*)(ws + OFF_H1);
  float* el   = (float*)(ws + OFF_EL);
  float* er   = (float*)(ws + OFF_ER);
  int* fillp  = (int*)(ws + OFF_H1);    // padded counters: H1 free until k_agg1
  int* rank   = (int*)(ws + OFF_RANK);  // own region (ws = 256 MiB)

  hipMemsetAsync(fillp, 0, (size_t)NN * 16 * 4, stream);  // zero padded counters

  // 1) fused prep: rank atomics + canon copies (+ zero scanall sync vars)
  hipLaunchKernelGGL(k_prep, dim3(PREP_GRID), dim3(256), 0, stream,
                     d_in[0], fx,
                     d_in[3], d_in[7], d_in[4], d_in[5], d_in[6],
                     d_in[8], d_in[9], d_in[10], d_in[11], d_in[12],
                     wc1, wc2, al1, ar1, b1, al2, ar2, b2, wp, bp,
                     dst, fillp, rank, flag, sync);

  // 2) fused 3-phase scan in one dispatch
  hipLaunchKernelGGL(k_scanall, dim3(NB_SCAN), dim3(1024), 0, stream,
                     fillp, bsum, boff, rowptr, sync);

  // 3) fused place + gemm L1 (el/er epilogue included)
  hipLaunchKernelGGL(k_gemmplace, dim3(GP_PLACE_B + GEMM_B), dim3(256), 0, stream,
                     fx, wc1, z, al1, ar1, el, er, src, dst, rowptr, rank, adj);

  // 4) layer-1 aggregation (residual+bias+ELU fused)
  hipLaunchKernelGGL((k_agg<1>), dim3(NN / 4), dim3(256), 0, stream, z, el, er, rowptr, adj,
                     fx, b1, h1, (us16*)nullptr, (us16*)nullptr, (void*)nullptr, flag);
  // 5) layer-2 gemm (el/er epilogue)
  hipLaunchKernelGGL(k_gemm, dim3(GEMM_B), dim3(256), 0, stream, h1, wc2, z,
                     al2, ar2, el, er);
  // 6) layer-2 aggregation (+ head-mean + projection + bp)
  hipLaunchKernelGGL((k_agg<2>), dim3(NN / 4), dim3(256), 0, stream, z, el, er, rowptr, adj,
                     h1, b2, (us16*)nullptr, wp, bp, d_out, flag);
}